// Round 1
// baseline (869.659 us; speedup 1.0000x reference)
//
#include <hip/hip_runtime.h>
#include <hip/hip_bf16.h>
#include <stdint.h>

// Problem constants
#define L3D 3
#define BD 2
#define CD 2048
#define HW 3600
#define CH 256
#define HWP 3712   // 29 * 128, padded hw
#define KD 6144    // L3D * CD  (bytes per row in fp8 An/Bn)
#define SP 3712    // padded support dim
#define LB6 6      // L3D*BD
#define NPLANE 12  // both inputs' (l,b) planes
#define NT 48      // K-tiles in main GEMM: KD / 128

typedef __attribute__((ext_vector_type(8))) short short8;
typedef __attribute__((ext_vector_type(4))) float f32x4;
typedef __attribute__((ext_vector_type(4))) int i32x4;
typedef __attribute__((ext_vector_type(8))) int i32x8;

__device__ __forceinline__ short f2bf(float v) {
  uint32_t x = __float_as_uint(v);
  uint32_t r = (x + 0x7FFFu + ((x >> 16) & 1u)) >> 16;   // RNE
  return (short)(r & 0xFFFFu);
}

__device__ __forceinline__ float bf2f(short s) {
  return __uint_as_float(((uint32_t)(uint16_t)s) << 16);
}

__device__ __forceinline__ void load_lds16(const void* g, void* l) {
  __builtin_amdgcn_global_load_lds(
      (const __attribute__((address_space(1))) void*)g,
      (__attribute__((address_space(3))) void*)l, 16, 0, 0);
}

// ---- Fused norm + normalize + transpose + fp8 cast, one kernel, 2 phases ----
// grid (57 q-tiles, 12 planes): planes 0-5 = fq -> An (w/ corr_weight), 6-11 = fs -> Bn.
// Phase 1: ssq over all 2048 channels for 64 q. Phase 2: re-read (LLC-hot),
// normalize, transpose to [b][q][l*CD+c] fp8 e4m3, PLAIN k order (K=128 MFMA layout).
__global__ __launch_bounds__(256) void fnt_k(const float* __restrict__ fq,
                                             const float* __restrict__ fs,
                                             const float* __restrict__ cw,
                                             uint8_t* __restrict__ An,
                                             uint8_t* __restrict__ Bn) {
  const int j = blockIdx.y;
  const int qt = blockIdx.x * 64;
  const bool isq = (j < LB6);
  const int lb = isq ? j : j - LB6;
  const int l = lb / BD, b = lb % BD;
  const float* x = (isq ? fq : fs) + (size_t)lb * CD * HW;
  uint8_t* dst = isq ? An : Bn;

  const int tid = threadIdx.x;
  const int tx = tid & 63, part = tid >> 6;
  const int q = qt + tx;

  // ---- phase 1: sum of squares (4 parts of 512 channels) ----
  float s0 = 0.f, s1 = 0.f, s2 = 0.f, s3 = 0.f;
  if (q < HW) {
    const float* p = x + (size_t)part * 512 * HW + q;
    for (int c = 0; c < 512; c += 4) {
      float v0 = p[(size_t)(c + 0) * HW];
      float v1 = p[(size_t)(c + 1) * HW];
      float v2 = p[(size_t)(c + 2) * HW];
      float v3 = p[(size_t)(c + 3) * HW];
      s0 += v0 * v0; s1 += v1 * v1; s2 += v2 * v2; s3 += v3 * v3;
    }
  }
  __shared__ float buf[256];
  __shared__ float ivs[64];
  buf[tid] = (s0 + s1) + (s2 + s3);
  __syncthreads();
  if (tid < 64) {
    float t = buf[tid] + buf[tid + 64] + buf[tid + 128] + buf[tid + 192];
    const float scale = isq ? (cw[l] * 32.0f) : 32.0f;  // fp8 range scaling
    ivs[tid] = (1.f / fmaxf(sqrtf(t), 1e-12f)) * scale;
  }

  // ---- phase 2: 32 c-tiles of 64x64, transpose + pack fp8 ----
  __shared__ float tile[64][65];
  const int wx = tid & 7, wy = tid >> 3;
  for (int ct = 0; ct < 32; ct++) {
    const float* px = x + (size_t)ct * 64 * HW;
    __syncthreads();   // tile free (also covers ivs write on first iter)
#pragma unroll
    for (int r = 0; r < 16; r++) {
      int cl = r * 4 + part;
      tile[cl][tx] = (q < HW) ? px[(size_t)cl * HW + q] : 0.f;
    }
    __syncthreads();
#pragma unroll
    for (int it = 0; it < 2; it++) {
      int qrow = wy + it * 32;
      int qq = qt + qrow;
      if (qq < HW) {
        float iv = ivs[qrow];
        float v[8];
#pragma unroll
        for (int jj = 0; jj < 8; jj++) v[jj] = tile[wx * 8 + jj][qrow] * iv;
        int lo = 0, hi = 0;
        lo = __builtin_amdgcn_cvt_pk_fp8_f32(v[0], v[1], lo, false);
        lo = __builtin_amdgcn_cvt_pk_fp8_f32(v[2], v[3], lo, true);
        hi = __builtin_amdgcn_cvt_pk_fp8_f32(v[4], v[5], hi, false);
        hi = __builtin_amdgcn_cvt_pk_fp8_f32(v[6], v[7], hi, true);
        int2 pk = make_int2(lo, hi);
        *reinterpret_cast<int2*>(dst + ((size_t)b * HWP + qq) * KD +
                                 (size_t)l * CD + ct * 64 + wx * 8) = pk;
      }
    }
  }
}

// ---------------- Main GEMM: MX-fp8 (scales=1.0), 256x256 tile, BK=128 ----------------
// 8-phase-style schedule (4 phases per K-tile, double-buffered LDS, burst prefetch):
//   ph0: ds_read A-half0 + B-half0; issue ALL 8 global_load_lds for tile t+1 into
//        buf^1; bar; lgkm; 8 MFMA (m0-3 x n0-1); bar
//   ph1: ds_read B-half1; bar; lgkm; 8 MFMA (m0-3 x n2-3); bar
//   ph2: ds_read A-half1 (overwrites A regs); bar; lgkm; 8 MFMA (m4-7 x n2-3); bar
//   ph3: no ds_read; bar; 8 MFMA (m4-7 x n0-1); vmcnt(0) [~3.5-phase lead]; bar
// Raw s_barrier (NOT __syncthreads) so the prefetch stays in flight across phases.
// LDS layout: row = 128 B = 8 chunks of 16 B; chunk c of row r lives at slot (c+r)&7
// -> fragment reads are 2-way (free) instead of 16-way conflicted.
__global__ __launch_bounds__(512, 2) void gemm_main(const uint8_t* __restrict__ A,
                                                    const uint8_t* __restrict__ B,
                                                    __hip_bfloat16* __restrict__ C) {
  const int bz = blockIdx.y;
  const int lin = blockIdx.x;            // 225 = 15*15, m-major (consecutive share A-panel)
  const int m_t = lin / 15, n_t = lin % 15;
  const int m0 = m_t * 256, n0 = n_t * 256;
  const int tid = threadIdx.x;
  const int lane = tid & 63;
  const int wv = tid >> 6;               // 0..7 waves: 2 (m) x 4 (n)

  __shared__ uint8_t lA[2][256 * 128];   // 64 KB
  __shared__ uint8_t lB[2][256 * 128];   // 64 KB   (total 128 KB, 1 block/CU)

  const uint8_t* gA = A + (size_t)bz * HWP * KD;
  const uint8_t* gB = B + (size_t)bz * HWP * KD;

  const int r_loc = tid >> 3;            // 0..63: row within a 64-row staging call
  const int slot = tid & 7;              // LDS slot within row
  const int csw = (slot - r_loc) & 7;    // global chunk this lane fetches
  const int wavebase = (tid & ~63) * 16; // wave-uniform LDS byte base

  const int wr = (wv >> 2) * 128;        // wave m offset: 0 / 128
  const int wc = (wv & 3) * 64;          // wave n offset: 0/64/128/192
  const int ml = lane & 15;
  const int kg = lane >> 4;              // k-group: 32 contiguous k bytes per lane

  f32x4 acc[8][4];
#pragma unroll
  for (int i = 0; i < 8; i++)
#pragma unroll
    for (int jj = 0; jj < 4; jj++) acc[i][jj] = (f32x4){0.f, 0.f, 0.f, 0.f};

  auto stage = [&](int t, int bufi) {
    const int k0 = t * 128;
#pragma unroll
    for (int i = 0; i < 4; i++) {
      load_lds16(gA + (size_t)(m0 + i * 64 + r_loc) * KD + k0 + csw * 16,
                 &lA[bufi][i * 8192 + wavebase]);
      load_lds16(gB + (size_t)(n0 + i * 64 + r_loc) * KD + k0 + csw * 16,
                 &lB[bufi][i * 8192 + wavebase]);
    }
  };

  auto rdfrag = [&](const uint8_t* base, int row) -> i32x8 {
    const uint8_t* rp = base + (row << 7);
    i32x4 lo = *reinterpret_cast<const i32x4*>(rp + (((kg * 2)     + row) & 7) * 16);
    i32x4 hi = *reinterpret_cast<const i32x4*>(rp + (((kg * 2 + 1) + row) & 7) * 16);
    return __builtin_shufflevector(lo, hi, 0, 1, 2, 3, 4, 5, 6, 7);
  };

  // prologue: stage tile 0, drain, barrier
  stage(0, 0);
  asm volatile("s_waitcnt vmcnt(0)" ::: "memory");
  __builtin_amdgcn_s_barrier();

  for (int t = 0; t < NT; t++) {
    const int cur = t & 1;
    const uint8_t* pA = lA[cur];
    const uint8_t* pB = lB[cur];
    const bool st = (t + 1 < NT);
    i32x8 af[4], bfr[4];

    // ---- phase 0: A-half0 + B-half0 frags; burst-prefetch tile t+1 ----
#pragma unroll
    for (int x = 0; x < 4; x++) af[x] = rdfrag(pA, wr + x * 16 + ml);
#pragma unroll
    for (int x = 0; x < 2; x++) bfr[x] = rdfrag(pB, wc + x * 16 + ml);
    if (st) stage(t + 1, cur ^ 1);
    __builtin_amdgcn_s_barrier();
    asm volatile("s_waitcnt lgkmcnt(0)");
    __builtin_amdgcn_s_setprio(1);
#pragma unroll
    for (int mt = 0; mt < 4; mt++)
#pragma unroll
      for (int nt = 0; nt < 2; nt++)
        acc[mt][nt] = __builtin_amdgcn_mfma_scale_f32_16x16x128_f8f6f4(
            af[mt], bfr[nt], acc[mt][nt], 0, 0, 0, 0x7F7F7F7F, 0, 0x7F7F7F7F);
    __builtin_amdgcn_s_setprio(0);
    __builtin_amdgcn_s_barrier();

    // ---- phase 1: B-half1 frags ----
#pragma unroll
    for (int x = 2; x < 4; x++) bfr[x] = rdfrag(pB, wc + x * 16 + ml);
    __builtin_amdgcn_s_barrier();
    asm volatile("s_waitcnt lgkmcnt(0)");
    __builtin_amdgcn_s_setprio(1);
#pragma unroll
    for (int mt = 0; mt < 4; mt++)
#pragma unroll
      for (int nt = 2; nt < 4; nt++)
        acc[mt][nt] = __builtin_amdgcn_mfma_scale_f32_16x16x128_f8f6f4(
            af[mt], bfr[nt], acc[mt][nt], 0, 0, 0, 0x7F7F7F7F, 0, 0x7F7F7F7F);
    __builtin_amdgcn_s_setprio(0);
    __builtin_amdgcn_s_barrier();

    // ---- phase 2: A-half1 frags (overwrite af) ----
#pragma unroll
    for (int x = 0; x < 4; x++) af[x] = rdfrag(pA, wr + 64 + x * 16 + ml);
    __builtin_amdgcn_s_barrier();
    asm volatile("s_waitcnt lgkmcnt(0)");
    __builtin_amdgcn_s_setprio(1);
#pragma unroll
    for (int mt = 0; mt < 4; mt++)
#pragma unroll
      for (int nt = 2; nt < 4; nt++)
        acc[4 + mt][nt] = __builtin_amdgcn_mfma_scale_f32_16x16x128_f8f6f4(
            af[mt], bfr[nt], acc[4 + mt][nt], 0, 0, 0, 0x7F7F7F7F, 0, 0x7F7F7F7F);
    __builtin_amdgcn_s_setprio(0);
    __builtin_amdgcn_s_barrier();

    // ---- phase 3: no ds_read; wait staged tile at the end ----
    __builtin_amdgcn_s_barrier();
    __builtin_amdgcn_s_setprio(1);
#pragma unroll
    for (int mt = 0; mt < 4; mt++)
#pragma unroll
      for (int nt = 0; nt < 2; nt++)
        acc[4 + mt][nt] = __builtin_amdgcn_mfma_scale_f32_16x16x128_f8f6f4(
            af[mt], bfr[nt], acc[4 + mt][nt], 0, 0, 0, 0x7F7F7F7F, 0, 0x7F7F7F7F);
    __builtin_amdgcn_s_setprio(0);
    if (st) asm volatile("s_waitcnt vmcnt(0)" ::: "memory");
    __builtin_amdgcn_s_barrier();
  }

  __hip_bfloat16* oc = C + (size_t)bz * HWP * SP;
  const int rq = (lane >> 4) * 4;
  const int cl = lane & 15;
#pragma unroll
  for (int mt = 0; mt < 8; mt++) {
    const int rb = m0 + wr + mt * 16 + rq;
#pragma unroll
    for (int nt = 0; nt < 4; nt++) {
      const int col = n0 + wc + nt * 16 + cl;
      if (col < SP) {
        f32x4 v = acc[mt][nt];
#pragma unroll
        for (int r = 0; r < 4; r++) {
          const int rr = rb + r;
          if (rr < HW) *reinterpret_cast<short*>(&oc[(size_t)rr * SP + col]) = f2bf(v[r]);
        }
      }
    }
  }
}

// ---------------- Row softmax: bf16 red -> bf16 attn (pad cols zeroed) ----------------
// short8-vectorized (G13): 3600 = 450 full chunks of 8, so valid chunks need no
// per-element masking; chunks 450..463 are pure pad -> zeros.
__global__ __launch_bounds__(256) void softmax_k(const __hip_bfloat16* __restrict__ red,
                                                 __hip_bfloat16* __restrict__ attn) {
  const int q = blockIdx.x;
  const int b = blockIdx.y;
  const __hip_bfloat16* row = red + ((size_t)b * HWP + q) * SP;
  __hip_bfloat16* orow = attn + ((size_t)b * HWP + q) * SP;
  const int tid = threadIdx.x;
  const int lane = tid & 63, wv = tid >> 6;
  const float SM = 20.0f / 1024.0f;   // undo 32*32 fp8 range scaling, apply temp

  float v0[8], v1[8];
  const int c1 = 256 + tid;           // second chunk id (valid when < 450)
  const bool has1 = (c1 < 450);

  float mx = -3.4e38f;
  {
    short8 pk = *reinterpret_cast<const short8*>(&row[(size_t)tid * 8]);
#pragma unroll
    for (int j = 0; j < 8; j++) { v0[j] = bf2f(pk[j]); mx = fmaxf(mx, v0[j]); }
  }
  if (has1) {
    short8 pk = *reinterpret_cast<const short8*>(&row[(size_t)c1 * 8]);
#pragma unroll
    for (int j = 0; j < 8; j++) { v1[j] = bf2f(pk[j]); mx = fmaxf(mx, v1[j]); }
  }
  for (int off = 32; off > 0; off >>= 1) mx = fmaxf(mx, __shfl_down(mx, off, 64));
  __shared__ float sm[4];
  if (lane == 0) sm[wv] = mx;
  __syncthreads();
  mx = fmaxf(fmaxf(sm[0], sm[1]), fmaxf(sm[2], sm[3]));

  float sum = 0.f;
#pragma unroll
  for (int j = 0; j < 8; j++) { float e = __expf((v0[j] - mx) * SM); v0[j] = e; sum += e; }
  if (has1) {
#pragma unroll
    for (int j = 0; j < 8; j++) { float e = __expf((v1[j] - mx) * SM); v1[j] = e; sum += e; }
  }
  for (int off = 32; off > 0; off >>= 1) sum += __shfl_down(sum, off, 64);
  __syncthreads();
  if (lane == 0) sm[wv] = sum;
  __syncthreads();
  const float inv = 1.f / (sm[0] + sm[1] + sm[2] + sm[3]);

  {
    short8 o;
#pragma unroll
    for (int j = 0; j < 8; j++) o[j] = f2bf(v0[j] * inv);
    *reinterpret_cast<short8*>(&orow[(size_t)tid * 8]) = o;
  }
  if (has1) {
    short8 o;
#pragma unroll
    for (int j = 0; j < 8; j++) o[j] = f2bf(v1[j] * inv);
    *reinterpret_cast<short8*>(&orow[(size_t)c1 * 8]) = o;
  } else if (c1 < 464) {            // pad chunks 450..463 -> zero (pv reads them)
    short8 z = {0, 0, 0, 0, 0, 0, 0, 0};
    *reinterpret_cast<short8*>(&orow[(size_t)c1 * 8]) = z;
  }
}

// ---------------- Cast f_s -> bf16 v, zero-pad s to SP ----------------
__global__ __launch_bounds__(256) void castv_k(const float* __restrict__ fs,
                                               __hip_bfloat16* __restrict__ vb) {
  const int idx = blockIdx.x * 256 + threadIdx.x;
  if (idx >= BD * CH * SP) return;
  const int s = idx % SP;
  const int bc = idx / SP;
  float v = (s < HW) ? fs[(size_t)bc * HW + s] : 0.f;
  *reinterpret_cast<short*>(&vb[idx]) = f2bf(v);
}

// ---------------- PV GEMM + blend epilogue, 128(c) x 64(q) tiles ----------------
__global__ __launch_bounds__(256, 2) void pv_gemm(const __hip_bfloat16* __restrict__ A,
                                                  const __hip_bfloat16* __restrict__ B,
                                                  const float* __restrict__ fqin,
                                                  float* __restrict__ out) {
  const int bz = blockIdx.z;
  const int m0 = blockIdx.y * 128;   // c tile (2)
  const int n0 = blockIdx.x * 64;    // q tile (58)
  const int tid = threadIdx.x;
  const int lane = tid & 63;
  const int wv = tid >> 6;

  __shared__ __hip_bfloat16 lA[128 * 32];   // 8 KB
  __shared__ __hip_bfloat16 lB[64 * 32];    // 4 KB

  const __hip_bfloat16* gA = A + (size_t)bz * CH * SP;
  const __hip_bfloat16* gB = B + (size_t)bz * HWP * SP;

  const int r0 = tid >> 2;
  const int kc = (tid & 3) * 8;       // elements
  const int wb = (tid & ~63) * 8;     // wave-uniform LDS element base

  const int wr = (wv >> 1) * 64;      // m offset within tile
  const int wc = (wv & 1) * 32;       // n offset within tile
  const int ml = lane & 15;
  const int kq = (lane >> 4) * 8;

  f32x4 acc[4][2];
#pragma unroll
  for (int i = 0; i < 4; i++)
#pragma unroll
    for (int jj = 0; jj < 2; jj++) acc[i][jj] = (f32x4){0.f, 0.f, 0.f, 0.f};

  for (int k0 = 0; k0 < SP; k0 += 32) {
    const __hip_bfloat16* pa0 = gA + (size_t)(m0 + r0) * SP + k0 + kc;
    const __hip_bfloat16* pb0 = gB + (size_t)(n0 + r0) * SP + k0 + kc;
    load_lds16(pa0, &lA[wb]);
    load_lds16(pa0 + (size_t)64 * SP, &lA[wb + 2048]);
    load_lds16(pb0, &lB[wb]);
    __syncthreads();

    short8 af[4], bfr[2];
#pragma unroll
    for (int t = 0; t < 4; t++)
      af[t] = *reinterpret_cast<const short8*>(&lA[(wr + t * 16 + ml) * 32 + kq]);
#pragma unroll
    for (int t = 0; t < 2; t++)
      bfr[t] = *reinterpret_cast<const short8*>(&lB[(wc + t * 16 + ml) * 32 + kq]);
#pragma unroll
    for (int mt = 0; mt < 4; mt++)
#pragma unroll
      for (int nt = 0; nt < 2; nt++)
        acc[mt][nt] = __builtin_amdgcn_mfma_f32_16x16x32_bf16(af[mt], bfr[nt], acc[mt][nt], 0, 0, 0);
    __syncthreads();
  }

  const size_t obase = (size_t)bz * CH * HW;
  const size_t attoff = (size_t)BD * CH * HW;
  const int rq = (lane >> 4) * 4;
  const int cl = lane & 15;
#pragma unroll
  for (int mt = 0; mt < 4; mt++) {
    const int rb = m0 + wr + mt * 16 + rq;   // c
#pragma unroll
    for (int nt = 0; nt < 2; nt++) {
      const int col = n0 + wc + nt * 16 + cl;  // q
      if (col < HW) {
        f32x4 v = acc[mt][nt];
#pragma unroll
        for (int r = 0; r < 4; r++) {
          const int c = rb + r;
          size_t oi = obase + (size_t)c * HW + col;
          float att = v[r];
          out[oi] = (fqin[oi] + 0.3f * att) * (1.0f / 1.3f);
          out[attoff + oi] = att;
        }
      }
    }
  }
}

extern "C" void kernel_launch(void* const* d_in, const int* in_sizes, int n_in,
                              void* d_out, int out_size, void* d_ws, size_t ws_size,
                              hipStream_t stream) {
  const float* fqf = (const float*)d_in[0];   // [L,B,C,H,W]
  const float* fsf = (const float*)d_in[1];
  const float* f_q = (const float*)d_in[2];   // [B,CH,H,W]
  const float* f_s = (const float*)d_in[3];
  const float* cw  = (const float*)d_in[4];   // [L]
  float* out = (float*)d_out;

  // workspace: An, Bn (fp8), red (bf16); attn + vb alias An/Bn after gemm
  char* w = (char*)d_ws;
  uint8_t* An = (uint8_t*)w;   w += (size_t)BD * HWP * KD;        // 45.6 MB
  uint8_t* Bn = (uint8_t*)w;   w += (size_t)BD * HWP * KD;        // 45.6 MB
  __hip_bfloat16* red = (__hip_bfloat16*)w;                       // 55.1 MB
  __hip_bfloat16* attn = (__hip_bfloat16*)An;                     // 55.1 of 91.2 MB
  __hip_bfloat16* vb = (__hip_bfloat16*)(An + (size_t)BD * HWP * SP * 2);  // 3.8 MB
  (void)ws_size; (void)in_sizes; (void)n_in; (void)out_size;

  fnt_k<<<dim3(57, NPLANE), 256, 0, stream>>>(fqf, fsf, cw, An, Bn);
  gemm_main<<<dim3(225, BD), 512, 0, stream>>>(An, Bn, red);
  softmax_k<<<dim3(HW, BD), 256, 0, stream>>>(red, attn);
  castv_k<<<(BD * CH * SP + 255) / 256, 256, 0, stream>>>(f_s, vb);
  pv_gemm<<<dim3(58, 2, BD), 256, 0, stream>>>(vb, attn, f_q, out);
}

// Round 2
// 809.136 us; speedup vs baseline: 1.0748x; 1.0748x over previous
//
#include <hip/hip_runtime.h>
#include <hip/hip_bf16.h>
#include <stdint.h>

// Problem constants
#define L3D 3
#define BD 2
#define CD 2048
#define HW 3600
#define CH 256
#define HWP 3712   // 29 * 128, padded hw
#define KD 6144    // L3D * CD  (bytes per row in fp8 An/Bn)
#define SP 3712    // padded support dim
#define SP2 3840   // partial-ssq q stride (covers qt up to 3836)
#define LB6 6      // L3D*BD
#define NPLANE 12  // both inputs' (l,b) planes
#define NT 48      // K-tiles in main GEMM: KD / 128

typedef __attribute__((ext_vector_type(8))) short short8;
typedef __attribute__((ext_vector_type(4))) float f32x4;
typedef __attribute__((ext_vector_type(4))) int i32x4;
typedef __attribute__((ext_vector_type(8))) int i32x8;

__device__ __forceinline__ short f2bf(float v) {
  uint32_t x = __float_as_uint(v);
  uint32_t r = (x + 0x7FFFu + ((x >> 16) & 1u)) >> 16;   // RNE
  return (short)(r & 0xFFFFu);
}

__device__ __forceinline__ float bf2f(short s) {
  return __uint_as_float(((uint32_t)(uint16_t)s) << 16);
}

__device__ __forceinline__ void load_lds16(const void* g, void* l) {
  __builtin_amdgcn_global_load_lds(
      (const __attribute__((address_space(1))) void*)g,
      (__attribute__((address_space(3))) void*)l, 16, 0, 0);
}

// ---------------- norm_k: sum-of-squares partials ----------------
// grid (15 q-tiles of 256, 12 planes, 8 c-splits of 256 ch), 256 thr.
// Lane = (qg = tid&63 -> 4 consecutive q via float4, cp = tid>>6 -> c stride 4).
// 4-deep float4 unroll = 4KB/wave in flight (latency-hiding fix vs old 1KB).
__global__ __launch_bounds__(256) void norm_k(const float* __restrict__ fq,
                                              const float* __restrict__ fs,
                                              float* __restrict__ part) {
  const int qt = blockIdx.x * 256;
  const int j = blockIdx.y;
  const int cs = blockIdx.z;
  const bool isq = (j < LB6);
  const int lb = isq ? j : j - LB6;
  const float* x = (isq ? fq : fs) + (size_t)lb * CD * HW;

  const int tid = threadIdx.x;
  const int qg = tid & 63;
  const int cp = tid >> 6;          // 0..3
  const int q4 = qt + qg * 4;

  f32x4 a0 = (f32x4){0.f, 0.f, 0.f, 0.f};
  f32x4 a1 = a0, a2 = a0, a3 = a0;
  if (q4 < HW) {                    // HW % 4 == 0: float4 fully valid or fully out
    const float* p = x + ((size_t)cs * 256 + cp) * HW + q4;
    for (int i = 0; i < 64; i += 4) {
      f32x4 v0 = *reinterpret_cast<const f32x4*>(p + (size_t)(i + 0) * 4 * HW);
      f32x4 v1 = *reinterpret_cast<const f32x4*>(p + (size_t)(i + 1) * 4 * HW);
      f32x4 v2 = *reinterpret_cast<const f32x4*>(p + (size_t)(i + 2) * 4 * HW);
      f32x4 v3 = *reinterpret_cast<const f32x4*>(p + (size_t)(i + 3) * 4 * HW);
      a0 += v0 * v0; a1 += v1 * v1; a2 += v2 * v2; a3 += v3 * v3;
    }
  }
  f32x4 a = (a0 + a1) + (a2 + a3);

  __shared__ float rb[4][256];
  *reinterpret_cast<f32x4*>(&rb[cp][qg * 4]) = a;
  __syncthreads();
  float s = rb[0][tid] + rb[1][tid] + rb[2][tid] + rb[3][tid];
  part[((size_t)cs * NPLANE + j) * SP2 + qt + tid] = s;
}

// ---------------- trans_k: normalize + transpose + fp8 pack ----------------
// grid (57 q-tiles of 64, 12 planes, 4 c-groups of 8 c-tiles): 2736 blocks ->
// ~8 blocks/CU (vs 2.7 before). Reduces the 8 ssq partials for its 64 q, then
// runs the proven LDS-transpose pack on its 8 c-tiles. Output numerics identical
// to the old fused fnt_k.
__global__ __launch_bounds__(256) void trans_k(const float* __restrict__ fq,
                                               const float* __restrict__ fs,
                                               const float* __restrict__ cw,
                                               const float* __restrict__ part,
                                               uint8_t* __restrict__ An,
                                               uint8_t* __restrict__ Bn) {
  const int j = blockIdx.y;
  const int qt = blockIdx.x * 64;
  const int cg = blockIdx.z;
  const bool isq = (j < LB6);
  const int lb = isq ? j : j - LB6;
  const int l = lb / BD, b = lb % BD;
  const float* x = (isq ? fq : fs) + (size_t)lb * CD * HW;
  uint8_t* dst = isq ? An : Bn;

  const int tid = threadIdx.x;

  __shared__ float ivs[64];
  if (tid < 64) {
    const int q = qt + tid;
    float s = 0.f;
#pragma unroll
    for (int cs = 0; cs < 8; cs++) s += part[((size_t)cs * NPLANE + j) * SP2 + q];
    const float scale = isq ? (cw[l] * 32.0f) : 32.0f;  // fp8 range scaling
    ivs[tid] = (1.f / fmaxf(sqrtf(s), 1e-12f)) * scale;
  }

  __shared__ float tile[64][65];
  const int tx = tid & 63, partid = tid >> 6;
  const int q = qt + tx;
  const int wx = tid & 7, wy = tid >> 3;

  for (int t = 0; t < 8; t++) {
    const int ct = cg * 8 + t;
    const float* px = x + (size_t)ct * 64 * HW;
    __syncthreads();   // tile free (also covers ivs write on first iter)
#pragma unroll
    for (int r = 0; r < 16; r++) {
      int cl = r * 4 + partid;
      tile[cl][tx] = (q < HW) ? px[(size_t)cl * HW + q] : 0.f;
    }
    __syncthreads();
#pragma unroll
    for (int it = 0; it < 2; it++) {
      int qrow = wy + it * 32;
      int qq = qt + qrow;
      if (qq < HW) {
        float iv = ivs[qrow];
        float v[8];
#pragma unroll
        for (int jj = 0; jj < 8; jj++) v[jj] = tile[wx * 8 + jj][qrow] * iv;
        int lo = 0, hi = 0;
        lo = __builtin_amdgcn_cvt_pk_fp8_f32(v[0], v[1], lo, false);
        lo = __builtin_amdgcn_cvt_pk_fp8_f32(v[2], v[3], lo, true);
        hi = __builtin_amdgcn_cvt_pk_fp8_f32(v[4], v[5], hi, false);
        hi = __builtin_amdgcn_cvt_pk_fp8_f32(v[6], v[7], hi, true);
        int2 pk = make_int2(lo, hi);
        *reinterpret_cast<int2*>(dst + ((size_t)b * HWP + qq) * KD +
                                 (size_t)l * CD + ct * 64 + wx * 8) = pk;
      }
    }
  }
}

// ---------------- Main GEMM: MX-fp8 (scales=1.0), 256x256 tile, BK=128 ----------------
// 4 phases per K-tile, double-buffered LDS, burst prefetch at ph0, vmcnt(0) at ph3 end.
// Raw s_barrier (NOT __syncthreads) so the prefetch stays in flight across phases.
// LDS layout: row = 128 B = 8 chunks of 16 B; chunk c of row r lives at slot (c+r)&7.
__global__ __launch_bounds__(512, 2) void gemm_main(const uint8_t* __restrict__ A,
                                                    const uint8_t* __restrict__ B,
                                                    __hip_bfloat16* __restrict__ C) {
  const int bz = blockIdx.y;
  const int lin = blockIdx.x;            // 225 = 15*15, m-major (consecutive share A-panel)
  const int m_t = lin / 15, n_t = lin % 15;
  const int m0 = m_t * 256, n0 = n_t * 256;
  const int tid = threadIdx.x;
  const int lane = tid & 63;
  const int wv = tid >> 6;               // 0..7 waves: 2 (m) x 4 (n)

  __shared__ uint8_t lA[2][256 * 128];   // 64 KB
  __shared__ uint8_t lB[2][256 * 128];   // 64 KB   (total 128 KB, 1 block/CU)

  const uint8_t* gA = A + (size_t)bz * HWP * KD;
  const uint8_t* gB = B + (size_t)bz * HWP * KD;

  const int r_loc = tid >> 3;            // 0..63: row within a 64-row staging call
  const int slot = tid & 7;              // LDS slot within row
  const int csw = (slot - r_loc) & 7;    // global chunk this lane fetches
  const int wavebase = (tid & ~63) * 16; // wave-uniform LDS byte base

  const int wr = (wv >> 2) * 128;        // wave m offset: 0 / 128
  const int wc = (wv & 3) * 64;          // wave n offset: 0/64/128/192
  const int ml = lane & 15;
  const int kg = lane >> 4;              // k-group: 32 contiguous k bytes per lane

  f32x4 acc[8][4];
#pragma unroll
  for (int i = 0; i < 8; i++)
#pragma unroll
    for (int jj = 0; jj < 4; jj++) acc[i][jj] = (f32x4){0.f, 0.f, 0.f, 0.f};

  auto stage = [&](int t, int bufi) {
    const int k0 = t * 128;
#pragma unroll
    for (int i = 0; i < 4; i++) {
      load_lds16(gA + (size_t)(m0 + i * 64 + r_loc) * KD + k0 + csw * 16,
                 &lA[bufi][i * 8192 + wavebase]);
      load_lds16(gB + (size_t)(n0 + i * 64 + r_loc) * KD + k0 + csw * 16,
                 &lB[bufi][i * 8192 + wavebase]);
    }
  };

  auto rdfrag = [&](const uint8_t* base, int row) -> i32x8 {
    const uint8_t* rp = base + (row << 7);
    i32x4 lo = *reinterpret_cast<const i32x4*>(rp + (((kg * 2)     + row) & 7) * 16);
    i32x4 hi = *reinterpret_cast<const i32x4*>(rp + (((kg * 2 + 1) + row) & 7) * 16);
    return __builtin_shufflevector(lo, hi, 0, 1, 2, 3, 4, 5, 6, 7);
  };

  // prologue: stage tile 0, drain, barrier
  stage(0, 0);
  asm volatile("s_waitcnt vmcnt(0)" ::: "memory");
  __builtin_amdgcn_s_barrier();

  for (int t = 0; t < NT; t++) {
    const int cur = t & 1;
    const uint8_t* pA = lA[cur];
    const uint8_t* pB = lB[cur];
    const bool st = (t + 1 < NT);
    i32x8 af[4], bfr[4];

    // ---- phase 0: A-half0 + B-half0 frags; burst-prefetch tile t+1 ----
#pragma unroll
    for (int x = 0; x < 4; x++) af[x] = rdfrag(pA, wr + x * 16 + ml);
#pragma unroll
    for (int x = 0; x < 2; x++) bfr[x] = rdfrag(pB, wc + x * 16 + ml);
    if (st) stage(t + 1, cur ^ 1);
    __builtin_amdgcn_s_barrier();
    asm volatile("s_waitcnt lgkmcnt(0)");
    __builtin_amdgcn_s_setprio(1);
#pragma unroll
    for (int mt = 0; mt < 4; mt++)
#pragma unroll
      for (int nt = 0; nt < 2; nt++)
        acc[mt][nt] = __builtin_amdgcn_mfma_scale_f32_16x16x128_f8f6f4(
            af[mt], bfr[nt], acc[mt][nt], 0, 0, 0, 0x7F7F7F7F, 0, 0x7F7F7F7F);
    __builtin_amdgcn_s_setprio(0);
    __builtin_amdgcn_s_barrier();

    // ---- phase 1: B-half1 frags ----
#pragma unroll
    for (int x = 2; x < 4; x++) bfr[x] = rdfrag(pB, wc + x * 16 + ml);
    __builtin_amdgcn_s_barrier();
    asm volatile("s_waitcnt lgkmcnt(0)");
    __builtin_amdgcn_s_setprio(1);
#pragma unroll
    for (int mt = 0; mt < 4; mt++)
#pragma unroll
      for (int nt = 2; nt < 4; nt++)
        acc[mt][nt] = __builtin_amdgcn_mfma_scale_f32_16x16x128_f8f6f4(
            af[mt], bfr[nt], acc[mt][nt], 0, 0, 0, 0x7F7F7F7F, 0, 0x7F7F7F7F);
    __builtin_amdgcn_s_setprio(0);
    __builtin_amdgcn_s_barrier();

    // ---- phase 2: A-half1 frags (overwrite af) ----
#pragma unroll
    for (int x = 0; x < 4; x++) af[x] = rdfrag(pA, wr + 64 + x * 16 + ml);
    __builtin_amdgcn_s_barrier();
    asm volatile("s_waitcnt lgkmcnt(0)");
    __builtin_amdgcn_s_setprio(1);
#pragma unroll
    for (int mt = 0; mt < 4; mt++)
#pragma unroll
      for (int nt = 2; nt < 4; nt++)
        acc[4 + mt][nt] = __builtin_amdgcn_mfma_scale_f32_16x16x128_f8f6f4(
            af[mt], bfr[nt], acc[4 + mt][nt], 0, 0, 0, 0x7F7F7F7F, 0, 0x7F7F7F7F);
    __builtin_amdgcn_s_setprio(0);
    __builtin_amdgcn_s_barrier();

    // ---- phase 3: no ds_read; wait staged tile at the end ----
    __builtin_amdgcn_s_barrier();
    __builtin_amdgcn_s_setprio(1);
#pragma unroll
    for (int mt = 0; mt < 4; mt++)
#pragma unroll
      for (int nt = 0; nt < 2; nt++)
        acc[4 + mt][nt] = __builtin_amdgcn_mfma_scale_f32_16x16x128_f8f6f4(
            af[mt], bfr[nt], acc[4 + mt][nt], 0, 0, 0, 0x7F7F7F7F, 0, 0x7F7F7F7F);
    __builtin_amdgcn_s_setprio(0);
    if (st) asm volatile("s_waitcnt vmcnt(0)" ::: "memory");
    __builtin_amdgcn_s_barrier();
  }

  __hip_bfloat16* oc = C + (size_t)bz * HWP * SP;
  const int rq = (lane >> 4) * 4;
  const int cl = lane & 15;
#pragma unroll
  for (int mt = 0; mt < 8; mt++) {
    const int rb = m0 + wr + mt * 16 + rq;
#pragma unroll
    for (int nt = 0; nt < 4; nt++) {
      const int col = n0 + wc + nt * 16 + cl;
      if (col < SP) {
        f32x4 v = acc[mt][nt];
#pragma unroll
        for (int r = 0; r < 4; r++) {
          const int rr = rb + r;
          if (rr < HW) *reinterpret_cast<short*>(&oc[(size_t)rr * SP + col]) = f2bf(v[r]);
        }
      }
    }
  }
}

// ---------------- Row softmax: bf16 red -> bf16 attn (pad cols zeroed) ----------------
__global__ __launch_bounds__(256) void softmax_k(const __hip_bfloat16* __restrict__ red,
                                                 __hip_bfloat16* __restrict__ attn) {
  const int q = blockIdx.x;
  const int b = blockIdx.y;
  const __hip_bfloat16* row = red + ((size_t)b * HWP + q) * SP;
  __hip_bfloat16* orow = attn + ((size_t)b * HWP + q) * SP;
  const int tid = threadIdx.x;
  const int lane = tid & 63, wv = tid >> 6;
  const float SM = 20.0f / 1024.0f;   // undo 32*32 fp8 range scaling, apply temp

  float v0[8], v1[8];
  const int c1 = 256 + tid;           // second chunk id (valid when < 450)
  const bool has1 = (c1 < 450);

  float mx = -3.4e38f;
  {
    short8 pk = *reinterpret_cast<const short8*>(&row[(size_t)tid * 8]);
#pragma unroll
    for (int j = 0; j < 8; j++) { v0[j] = bf2f(pk[j]); mx = fmaxf(mx, v0[j]); }
  }
  if (has1) {
    short8 pk = *reinterpret_cast<const short8*>(&row[(size_t)c1 * 8]);
#pragma unroll
    for (int j = 0; j < 8; j++) { v1[j] = bf2f(pk[j]); mx = fmaxf(mx, v1[j]); }
  }
  for (int off = 32; off > 0; off >>= 1) mx = fmaxf(mx, __shfl_down(mx, off, 64));
  __shared__ float sm[4];
  if (lane == 0) sm[wv] = mx;
  __syncthreads();
  mx = fmaxf(fmaxf(sm[0], sm[1]), fmaxf(sm[2], sm[3]));

  float sum = 0.f;
#pragma unroll
  for (int j = 0; j < 8; j++) { float e = __expf((v0[j] - mx) * SM); v0[j] = e; sum += e; }
  if (has1) {
#pragma unroll
    for (int j = 0; j < 8; j++) { float e = __expf((v1[j] - mx) * SM); v1[j] = e; sum += e; }
  }
  for (int off = 32; off > 0; off >>= 1) sum += __shfl_down(sum, off, 64);
  __syncthreads();
  if (lane == 0) sm[wv] = sum;
  __syncthreads();
  const float inv = 1.f / (sm[0] + sm[1] + sm[2] + sm[3]);

  {
    short8 o;
#pragma unroll
    for (int j = 0; j < 8; j++) o[j] = f2bf(v0[j] * inv);
    *reinterpret_cast<short8*>(&orow[(size_t)tid * 8]) = o;
  }
  if (has1) {
    short8 o;
#pragma unroll
    for (int j = 0; j < 8; j++) o[j] = f2bf(v1[j] * inv);
    *reinterpret_cast<short8*>(&orow[(size_t)c1 * 8]) = o;
  } else if (c1 < 464) {            // pad chunks 450..463 -> zero (pv reads them)
    short8 z = {0, 0, 0, 0, 0, 0, 0, 0};
    *reinterpret_cast<short8*>(&orow[(size_t)c1 * 8]) = z;
  }
}

// ---------------- Cast f_s -> bf16 v, zero-pad s to SP ----------------
__global__ __launch_bounds__(256) void castv_k(const float* __restrict__ fs,
                                               __hip_bfloat16* __restrict__ vb) {
  const int idx = blockIdx.x * 256 + threadIdx.x;
  if (idx >= BD * CH * SP) return;
  const int s = idx % SP;
  const int bc = idx / SP;
  float v = (s < HW) ? fs[(size_t)bc * HW + s] : 0.f;
  *reinterpret_cast<short*>(&vb[idx]) = f2bf(v);
}

// ---------------- PV GEMM + blend epilogue, 128(c) x 64(q) tiles ----------------
__global__ __launch_bounds__(256, 2) void pv_gemm(const __hip_bfloat16* __restrict__ A,
                                                  const __hip_bfloat16* __restrict__ B,
                                                  const float* __restrict__ fqin,
                                                  float* __restrict__ out) {
  const int bz = blockIdx.z;
  const int m0 = blockIdx.y * 128;   // c tile (2)
  const int n0 = blockIdx.x * 64;    // q tile (58)
  const int tid = threadIdx.x;
  const int lane = tid & 63;
  const int wv = tid >> 6;

  __shared__ __hip_bfloat16 lA[128 * 32];   // 8 KB
  __shared__ __hip_bfloat16 lB[64 * 32];    // 4 KB

  const __hip_bfloat16* gA = A + (size_t)bz * CH * SP;
  const __hip_bfloat16* gB = B + (size_t)bz * HWP * SP;

  const int r0 = tid >> 2;
  const int kc = (tid & 3) * 8;       // elements
  const int wb = (tid & ~63) * 8;     // wave-uniform LDS element base

  const int wr = (wv >> 1) * 64;      // m offset within tile
  const int wc = (wv & 1) * 32;       // n offset within tile
  const int ml = lane & 15;
  const int kq = (lane >> 4) * 8;

  f32x4 acc[4][2];
#pragma unroll
  for (int i = 0; i < 4; i++)
#pragma unroll
    for (int jj = 0; jj < 2; jj++) acc[i][jj] = (f32x4){0.f, 0.f, 0.f, 0.f};

  for (int k0 = 0; k0 < SP; k0 += 32) {
    const __hip_bfloat16* pa0 = gA + (size_t)(m0 + r0) * SP + k0 + kc;
    const __hip_bfloat16* pb0 = gB + (size_t)(n0 + r0) * SP + k0 + kc;
    load_lds16(pa0, &lA[wb]);
    load_lds16(pa0 + (size_t)64 * SP, &lA[wb + 2048]);
    load_lds16(pb0, &lB[wb]);
    __syncthreads();

    short8 af[4], bfr[2];
#pragma unroll
    for (int t = 0; t < 4; t++)
      af[t] = *reinterpret_cast<const short8*>(&lA[(wr + t * 16 + ml) * 32 + kq]);
#pragma unroll
    for (int t = 0; t < 2; t++)
      bfr[t] = *reinterpret_cast<const short8*>(&lB[(wc + t * 16 + ml) * 32 + kq]);
#pragma unroll
    for (int mt = 0; mt < 4; mt++)
#pragma unroll
      for (int nt = 0; nt < 2; nt++)
        acc[mt][nt] = __builtin_amdgcn_mfma_f32_16x16x32_bf16(af[mt], bfr[nt], acc[mt][nt], 0, 0, 0);
    __syncthreads();
  }

  const size_t obase = (size_t)bz * CH * HW;
  const size_t attoff = (size_t)BD * CH * HW;
  const int rq = (lane >> 4) * 4;
  const int cl = lane & 15;
#pragma unroll
  for (int mt = 0; mt < 4; mt++) {
    const int rb = m0 + wr + mt * 16 + rq;   // c
#pragma unroll
    for (int nt = 0; nt < 2; nt++) {
      const int col = n0 + wc + nt * 16 + cl;  // q
      if (col < HW) {
        f32x4 v = acc[mt][nt];
#pragma unroll
        for (int r = 0; r < 4; r++) {
          const int c = rb + r;
          size_t oi = obase + (size_t)c * HW + col;
          float att = v[r];
          out[oi] = (fqin[oi] + 0.3f * att) * (1.0f / 1.3f);
          out[attoff + oi] = att;
        }
      }
    }
  }
}

extern "C" void kernel_launch(void* const* d_in, const int* in_sizes, int n_in,
                              void* d_out, int out_size, void* d_ws, size_t ws_size,
                              hipStream_t stream) {
  const float* fqf = (const float*)d_in[0];   // [L,B,C,H,W]
  const float* fsf = (const float*)d_in[1];
  const float* f_q = (const float*)d_in[2];   // [B,CH,H,W]
  const float* f_s = (const float*)d_in[3];
  const float* cw  = (const float*)d_in[4];   // [L]
  float* out = (float*)d_out;

  // workspace: An, Bn (fp8), red (bf16), part (ssq partials);
  // attn + vb alias An/Bn after gemm
  char* w = (char*)d_ws;
  uint8_t* An = (uint8_t*)w;   w += (size_t)BD * HWP * KD;        // 45.6 MB
  uint8_t* Bn = (uint8_t*)w;   w += (size_t)BD * HWP * KD;        // 45.6 MB
  __hip_bfloat16* red = (__hip_bfloat16*)w;  w += (size_t)BD * HWP * SP * 2;  // 55.1 MB
  float* part = (float*)w;                                        // 1.5 MB
  __hip_bfloat16* attn = (__hip_bfloat16*)An;                     // 55.1 of 91.2 MB
  __hip_bfloat16* vb = (__hip_bfloat16*)(An + (size_t)BD * HWP * SP * 2);  // 3.8 MB
  (void)ws_size; (void)in_sizes; (void)n_in; (void)out_size;

  norm_k<<<dim3(15, NPLANE, 8), 256, 0, stream>>>(fqf, fsf, part);
  trans_k<<<dim3(57, NPLANE, 4), 256, 0, stream>>>(fqf, fsf, cw, part, An, Bn);
  gemm_main<<<dim3(225, BD), 512, 0, stream>>>(An, Bn, red);
  softmax_k<<<dim3(HW, BD), 256, 0, stream>>>(red, attn);
  castv_k<<<(BD * CH * SP + 255) / 256, 256, 0, stream>>>(f_s, vb);
  pv_gemm<<<dim3(58, 2, BD), 256, 0, stream>>>(vb, attn, f_q, out);
}

// Round 3
// 800.660 us; speedup vs baseline: 1.0862x; 1.0106x over previous
//
#include <hip/hip_runtime.h>
#include <hip/hip_bf16.h>
#include <stdint.h>

// Problem constants
#define L3D 3
#define BD 2
#define CD 2048
#define HW 3600
#define CH 256
#define HWP 3712   // 29 * 128, padded hw
#define KD 6144    // L3D * CD  (bytes per row in fp8 An/Bn)
#define SP 3712    // padded support dim
#define SP2 3840   // partial-ssq q stride
#define LB6 6      // L3D*BD
#define NPLANE 12  // both inputs' (l,b) planes
#define NT 48      // K-tiles in main GEMM: KD / 128
#define PVNT 58    // K-steps in PV GEMM: SP / 64

typedef __attribute__((ext_vector_type(8))) short short8;
typedef __attribute__((ext_vector_type(4))) float f32x4;
typedef __attribute__((ext_vector_type(4))) int i32x4;
typedef __attribute__((ext_vector_type(8))) int i32x8;

__device__ __forceinline__ short f2bf(float v) {
  uint32_t x = __float_as_uint(v);
  uint32_t r = (x + 0x7FFFu + ((x >> 16) & 1u)) >> 16;   // RNE
  return (short)(r & 0xFFFFu);
}

__device__ __forceinline__ float bf2f(short s) {
  return __uint_as_float(((uint32_t)(uint16_t)s) << 16);
}

__device__ __forceinline__ void load_lds16(const void* g, void* l) {
  __builtin_amdgcn_global_load_lds(
      (const __attribute__((address_space(1))) void*)g,
      (__attribute__((address_space(3))) void*)l, 16, 0, 0);
}

// ---------------- norm_k: sum-of-squares partials ----------------
__global__ __launch_bounds__(256) void norm_k(const float* __restrict__ fq,
                                              const float* __restrict__ fs,
                                              float* __restrict__ part) {
  const int qt = blockIdx.x * 256;
  const int j = blockIdx.y;
  const int cs = blockIdx.z;
  const bool isq = (j < LB6);
  const int lb = isq ? j : j - LB6;
  const float* x = (isq ? fq : fs) + (size_t)lb * CD * HW;

  const int tid = threadIdx.x;
  const int qg = tid & 63;
  const int cp = tid >> 6;          // 0..3
  const int q4 = qt + qg * 4;

  f32x4 a0 = (f32x4){0.f, 0.f, 0.f, 0.f};
  f32x4 a1 = a0, a2 = a0, a3 = a0;
  if (q4 < HW) {                    // HW % 4 == 0: float4 fully valid or fully out
    const float* p = x + ((size_t)cs * 256 + cp) * HW + q4;
    for (int i = 0; i < 64; i += 4) {
      f32x4 v0 = *reinterpret_cast<const f32x4*>(p + (size_t)(i + 0) * 4 * HW);
      f32x4 v1 = *reinterpret_cast<const f32x4*>(p + (size_t)(i + 1) * 4 * HW);
      f32x4 v2 = *reinterpret_cast<const f32x4*>(p + (size_t)(i + 2) * 4 * HW);
      f32x4 v3 = *reinterpret_cast<const f32x4*>(p + (size_t)(i + 3) * 4 * HW);
      a0 += v0 * v0; a1 += v1 * v1; a2 += v2 * v2; a3 += v3 * v3;
    }
  }
  f32x4 a = (a0 + a1) + (a2 + a3);

  __shared__ float rb[4][256];
  *reinterpret_cast<f32x4*>(&rb[cp][qg * 4]) = a;
  __syncthreads();
  float s = rb[0][tid] + rb[1][tid] + rb[2][tid] + rb[3][tid];
  part[((size_t)cs * NPLANE + j) * SP2 + qt + tid] = s;
}

// ---------------- trans_k: normalize + transpose + fp8 pack ----------------
__global__ __launch_bounds__(256) void trans_k(const float* __restrict__ fq,
                                               const float* __restrict__ fs,
                                               const float* __restrict__ cw,
                                               const float* __restrict__ part,
                                               uint8_t* __restrict__ An,
                                               uint8_t* __restrict__ Bn) {
  const int j = blockIdx.y;
  const int qt = blockIdx.x * 64;
  const int cg = blockIdx.z;
  const bool isq = (j < LB6);
  const int lb = isq ? j : j - LB6;
  const int l = lb / BD, b = lb % BD;
  const float* x = (isq ? fq : fs) + (size_t)lb * CD * HW;
  uint8_t* dst = isq ? An : Bn;

  const int tid = threadIdx.x;

  __shared__ float ivs[64];
  if (tid < 64) {
    const int q = qt + tid;
    float s = 0.f;
#pragma unroll
    for (int cs = 0; cs < 8; cs++) s += part[((size_t)cs * NPLANE + j) * SP2 + q];
    const float scale = isq ? (cw[l] * 32.0f) : 32.0f;  // fp8 range scaling
    ivs[tid] = (1.f / fmaxf(sqrtf(s), 1e-12f)) * scale;
  }

  __shared__ float tile[64][65];
  const int tx = tid & 63, partid = tid >> 6;
  const int q = qt + tx;
  const int wx = tid & 7, wy = tid >> 3;

  for (int t = 0; t < 8; t++) {
    const int ct = cg * 8 + t;
    const float* px = x + (size_t)ct * 64 * HW;
    __syncthreads();
#pragma unroll
    for (int r = 0; r < 16; r++) {
      int cl = r * 4 + partid;
      tile[cl][tx] = (q < HW) ? px[(size_t)cl * HW + q] : 0.f;
    }
    __syncthreads();
#pragma unroll
    for (int it = 0; it < 2; it++) {
      int qrow = wy + it * 32;
      int qq = qt + qrow;
      if (qq < HW) {
        float iv = ivs[qrow];
        float v[8];
#pragma unroll
        for (int jj = 0; jj < 8; jj++) v[jj] = tile[wx * 8 + jj][qrow] * iv;
        int lo = 0, hi = 0;
        lo = __builtin_amdgcn_cvt_pk_fp8_f32(v[0], v[1], lo, false);
        lo = __builtin_amdgcn_cvt_pk_fp8_f32(v[2], v[3], lo, true);
        hi = __builtin_amdgcn_cvt_pk_fp8_f32(v[4], v[5], hi, false);
        hi = __builtin_amdgcn_cvt_pk_fp8_f32(v[6], v[7], hi, true);
        int2 pk = make_int2(lo, hi);
        *reinterpret_cast<int2*>(dst + ((size_t)b * HWP + qq) * KD +
                                 (size_t)l * CD + ct * 64 + wx * 8) = pk;
      }
    }
  }
}

// ---------------- Main GEMM: MX-fp8, 256x256 tile, BK=128, T4 counted vmcnt ----------------
// Staging split into 4 half-stages (2 loads each) spread one-per-phase, 5-phase lead:
//   tile t: ph0 stages A(t+1)h1, ph1 B(t+1)h0, ph2 B(t+1)h1, ph3 A(t+2)h0.
// A(t+2)h0 can target tile t's own buffer at ph3 because all reads of tile t are
// certified complete by ph2's post-MFMA barrier. Steady-state wait: vmcnt(2) once
// per K-tile (leaves A(t+2)h0's 2 loads in flight) -- NEVER 0 in the main loop.
// Bijective XCD swizzle (450 blocks): consecutive wgid (m-major, A-panel-sharing)
// land on the same XCD's L2.
__global__ __launch_bounds__(512, 2) void gemm_main(const uint8_t* __restrict__ A,
                                                    const uint8_t* __restrict__ B,
                                                    __hip_bfloat16* __restrict__ C) {
  // --- bijective XCD swizzle: 450 = 8*56 + 2 -> chunks {57,57,56,56,56,56,56,56}
  const int orig = blockIdx.x;
  const int xcd = orig & 7, idx = orig >> 3;
  const int wg = (xcd < 2 ? xcd * 57 : 114 + (xcd - 2) * 56) + idx;
  const int bz = wg / 225;
  const int lin = wg % 225;
  const int m_t = lin / 15, n_t = lin % 15;   // m-major: 15 consecutive share A-panel
  const int m0 = m_t * 256, n0 = n_t * 256;
  const int tid = threadIdx.x;
  const int lane = tid & 63;
  const int wv = tid >> 6;               // 0..7 waves: 2 (m) x 4 (n)

  __shared__ uint8_t lA[2][256 * 128];   // 64 KB
  __shared__ uint8_t lB[2][256 * 128];   // 64 KB

  const uint8_t* gA = A + (size_t)bz * HWP * KD;
  const uint8_t* gB = B + (size_t)bz * HWP * KD;

  const int r_loc = tid >> 3;            // 0..63: row within a 64-row staging call
  const int slot = tid & 7;              // LDS slot within row
  const int csw = (slot - r_loc) & 7;    // global chunk this lane fetches
  const int wavebase = (tid & ~63) * 16; // wave-uniform LDS byte base

  const int wr = (wv >> 2) * 128;        // wave m offset: 0 / 128
  const int wc = (wv & 3) * 64;          // wave n offset: 0/64/128/192
  const int ml = lane & 15;
  const int kg = lane >> 4;              // k-group: 32 contiguous k bytes per lane

  f32x4 acc[8][4];
#pragma unroll
  for (int i = 0; i < 8; i++)
#pragma unroll
    for (int jj = 0; jj < 4; jj++) acc[i][jj] = (f32x4){0.f, 0.f, 0.f, 0.f};

  // one 64-row staging call (2 per half-tile)
  auto stA = [&](int t, int bufi, int i) {
    load_lds16(gA + (size_t)(m0 + i * 64 + r_loc) * KD + t * 128 + csw * 16,
               &lA[bufi][i * 8192 + wavebase]);
  };
  auto stB = [&](int t, int bufi, int i) {
    load_lds16(gB + (size_t)(n0 + i * 64 + r_loc) * KD + t * 128 + csw * 16,
               &lB[bufi][i * 8192 + wavebase]);
  };

  auto rdfrag = [&](const uint8_t* base, int row) -> i32x8 {
    const uint8_t* rp = base + (row << 7);
    i32x4 lo = *reinterpret_cast<const i32x4*>(rp + (((kg * 2)     + row) & 7) * 16);
    i32x4 hi = *reinterpret_cast<const i32x4*>(rp + (((kg * 2 + 1) + row) & 7) * 16);
    return __builtin_shufflevector(lo, hi, 0, 1, 2, 3, 4, 5, 6, 7);
  };

  // prologue: full tile 0 (8 loads) + A(1)h0 (2 loads); wait tile0 -> vmcnt(2)
  stA(0, 0, 0); stA(0, 0, 1); stA(0, 0, 2); stA(0, 0, 3);
  stB(0, 0, 0); stB(0, 0, 1); stB(0, 0, 2); stB(0, 0, 3);
  stA(1, 1, 0); stA(1, 1, 1);
  asm volatile("s_waitcnt vmcnt(2)" ::: "memory");
  __builtin_amdgcn_s_barrier();

  for (int t = 0; t < NT; t++) {
    const int cur = t & 1;
    const int nxt = cur ^ 1;
    const uint8_t* pA = lA[cur];
    const uint8_t* pB = lB[cur];
    const bool s1 = (t + 1 < NT);
    const bool s2 = (t + 2 < NT);
    i32x8 af[4], bfr[4];

    // ---- phase 0: A m-low + B n-low frags; stage A(t+1)h1 ----
#pragma unroll
    for (int x = 0; x < 4; x++) af[x] = rdfrag(pA, wr + x * 16 + ml);
#pragma unroll
    for (int x = 0; x < 2; x++) bfr[x] = rdfrag(pB, wc + x * 16 + ml);
    if (s1) { stA(t + 1, nxt, 2); stA(t + 1, nxt, 3); }
    __builtin_amdgcn_s_barrier();
    asm volatile("s_waitcnt lgkmcnt(0)");
    __builtin_amdgcn_s_setprio(1);
#pragma unroll
    for (int mt = 0; mt < 4; mt++)
#pragma unroll
      for (int nt = 0; nt < 2; nt++)
        acc[mt][nt] = __builtin_amdgcn_mfma_scale_f32_16x16x128_f8f6f4(
            af[mt], bfr[nt], acc[mt][nt], 0, 0, 0, 0x7F7F7F7F, 0, 0x7F7F7F7F);
    __builtin_amdgcn_s_setprio(0);
    __builtin_amdgcn_s_barrier();

    // ---- phase 1: B n-high frags; stage B(t+1)h0 ----
#pragma unroll
    for (int x = 2; x < 4; x++) bfr[x] = rdfrag(pB, wc + x * 16 + ml);
    if (s1) { stB(t + 1, nxt, 0); stB(t + 1, nxt, 1); }
    __builtin_amdgcn_s_barrier();
    asm volatile("s_waitcnt lgkmcnt(0)");
    __builtin_amdgcn_s_setprio(1);
#pragma unroll
    for (int mt = 0; mt < 4; mt++)
#pragma unroll
      for (int nt = 2; nt < 4; nt++)
        acc[mt][nt] = __builtin_amdgcn_mfma_scale_f32_16x16x128_f8f6f4(
            af[mt], bfr[nt], acc[mt][nt], 0, 0, 0, 0x7F7F7F7F, 0, 0x7F7F7F7F);
    __builtin_amdgcn_s_setprio(0);
    __builtin_amdgcn_s_barrier();

    // ---- phase 2: A m-high frags; stage B(t+1)h1 ----
#pragma unroll
    for (int x = 0; x < 4; x++) af[x] = rdfrag(pA, wr + 64 + x * 16 + ml);
    if (s1) { stB(t + 1, nxt, 2); stB(t + 1, nxt, 3); }
    __builtin_amdgcn_s_barrier();
    asm volatile("s_waitcnt lgkmcnt(0)");
    __builtin_amdgcn_s_setprio(1);
#pragma unroll
    for (int mt = 0; mt < 4; mt++)
#pragma unroll
      for (int nt = 2; nt < 4; nt++)
        acc[4 + mt][nt] = __builtin_amdgcn_mfma_scale_f32_16x16x128_f8f6f4(
            af[mt], bfr[nt], acc[4 + mt][nt], 0, 0, 0, 0x7F7F7F7F, 0, 0x7F7F7F7F);
    __builtin_amdgcn_s_setprio(0);
    __builtin_amdgcn_s_barrier();

    // ---- phase 3: no ds_read; stage A(t+2)h0 into CUR buffer (t's reads done);
    //      counted wait: leave A(t+2)h0 in flight ----
    if (s2) { stA(t + 2, cur, 0); stA(t + 2, cur, 1); }
    __builtin_amdgcn_s_barrier();
    __builtin_amdgcn_s_setprio(1);
#pragma unroll
    for (int mt = 0; mt < 4; mt++)
#pragma unroll
      for (int nt = 0; nt < 2; nt++)
        acc[4 + mt][nt] = __builtin_amdgcn_mfma_scale_f32_16x16x128_f8f6f4(
            af[mt], bfr[nt], acc[4 + mt][nt], 0, 0, 0, 0x7F7F7F7F, 0, 0x7F7F7F7F);
    __builtin_amdgcn_s_setprio(0);
    if (s2)      asm volatile("s_waitcnt vmcnt(2)" ::: "memory");
    else if (s1) asm volatile("s_waitcnt vmcnt(0)" ::: "memory");
    __builtin_amdgcn_s_barrier();
  }

  __hip_bfloat16* oc = C + (size_t)bz * HWP * SP;
  const int rq = (lane >> 4) * 4;
  const int cl = lane & 15;
#pragma unroll
  for (int mt = 0; mt < 8; mt++) {
    const int rb = m0 + wr + mt * 16 + rq;
#pragma unroll
    for (int nt = 0; nt < 4; nt++) {
      const int col = n0 + wc + nt * 16 + cl;
      if (col < SP) {
        f32x4 v = acc[mt][nt];
#pragma unroll
        for (int r = 0; r < 4; r++) {
          const int rr = rb + r;
          if (rr < HW) *reinterpret_cast<short*>(&oc[(size_t)rr * SP + col]) = f2bf(v[r]);
        }
      }
    }
  }
}

// ---------------- Row softmax: bf16 red -> bf16 attn (pad cols zeroed) ----------------
__global__ __launch_bounds__(256) void softmax_k(const __hip_bfloat16* __restrict__ red,
                                                 __hip_bfloat16* __restrict__ attn) {
  const int q = blockIdx.x;
  const int b = blockIdx.y;
  const __hip_bfloat16* row = red + ((size_t)b * HWP + q) * SP;
  __hip_bfloat16* orow = attn + ((size_t)b * HWP + q) * SP;
  const int tid = threadIdx.x;
  const int lane = tid & 63, wv = tid >> 6;
  const float SM = 20.0f / 1024.0f;   // undo 32*32 fp8 range scaling, apply temp

  float v0[8], v1[8];
  const int c1 = 256 + tid;           // second chunk id (valid when < 450)
  const bool has1 = (c1 < 450);

  float mx = -3.4e38f;
  {
    short8 pk = *reinterpret_cast<const short8*>(&row[(size_t)tid * 8]);
#pragma unroll
    for (int j = 0; j < 8; j++) { v0[j] = bf2f(pk[j]); mx = fmaxf(mx, v0[j]); }
  }
  if (has1) {
    short8 pk = *reinterpret_cast<const short8*>(&row[(size_t)c1 * 8]);
#pragma unroll
    for (int j = 0; j < 8; j++) { v1[j] = bf2f(pk[j]); mx = fmaxf(mx, v1[j]); }
  }
  for (int off = 32; off > 0; off >>= 1) mx = fmaxf(mx, __shfl_down(mx, off, 64));
  __shared__ float sm[4];
  if (lane == 0) sm[wv] = mx;
  __syncthreads();
  mx = fmaxf(fmaxf(sm[0], sm[1]), fmaxf(sm[2], sm[3]));

  float sum = 0.f;
#pragma unroll
  for (int j = 0; j < 8; j++) { float e = __expf((v0[j] - mx) * SM); v0[j] = e; sum += e; }
  if (has1) {
#pragma unroll
    for (int j = 0; j < 8; j++) { float e = __expf((v1[j] - mx) * SM); v1[j] = e; sum += e; }
  }
  for (int off = 32; off > 0; off >>= 1) sum += __shfl_down(sum, off, 64);
  __syncthreads();
  if (lane == 0) sm[wv] = sum;
  __syncthreads();
  const float inv = 1.f / (sm[0] + sm[1] + sm[2] + sm[3]);

  {
    short8 o;
#pragma unroll
    for (int j = 0; j < 8; j++) o[j] = f2bf(v0[j] * inv);
    *reinterpret_cast<short8*>(&orow[(size_t)tid * 8]) = o;
  }
  if (has1) {
    short8 o;
#pragma unroll
    for (int j = 0; j < 8; j++) o[j] = f2bf(v1[j] * inv);
    *reinterpret_cast<short8*>(&orow[(size_t)c1 * 8]) = o;
  } else if (c1 < 464) {            // pad chunks 450..463 -> zero (pv reads them)
    short8 z = {0, 0, 0, 0, 0, 0, 0, 0};
    *reinterpret_cast<short8*>(&orow[(size_t)c1 * 8]) = z;
  }
}

// ---------------- Cast f_s -> bf16 v, zero-pad s to SP ----------------
__global__ __launch_bounds__(256) void castv_k(const float* __restrict__ fs,
                                               __hip_bfloat16* __restrict__ vb) {
  const int idx = blockIdx.x * 256 + threadIdx.x;
  if (idx >= BD * CH * SP) return;
  const int s = idx % SP;
  const int bc = idx / SP;
  float v = (s < HW) ? fs[(size_t)bc * HW + s] : 0.f;
  *reinterpret_cast<short*>(&vb[idx]) = f2bf(v);
}

// ---------------- PV GEMM + blend epilogue, 128(c) x 64(q), BK=64, 2-phase dbuf ----
// T3-minimum: stage(t+1) -> ds_read/MFMA(t) -> vmcnt(0) -> s_barrier, one barrier
// per K-step (reads drained by MFMA dataflow before the barrier). LDS rows are
// 128 B with the (chunk+row)&7 swizzle so 16-lane frag reads are 2-way (free)
// instead of 16-way conflicted; swizzle applied on the GLOBAL source (rule #21).
__global__ __launch_bounds__(256, 2) void pv_gemm(const __hip_bfloat16* __restrict__ A,
                                                  const __hip_bfloat16* __restrict__ B,
                                                  const float* __restrict__ fqin,
                                                  float* __restrict__ out) {
  const int bz = blockIdx.z;
  const int m0 = blockIdx.y * 128;   // c tile (2)
  const int n0 = blockIdx.x * 64;    // q tile (58)
  const int tid = threadIdx.x;
  const int lane = tid & 63;
  const int wv = tid >> 6;

  __shared__ uint8_t lA[2][128 * 128];   // 16 KB each: 128 c-rows x 128 B (BK=64 bf16)
  __shared__ uint8_t lB[2][64 * 128];    // 8 KB each   -> 48 KB total

  const uint8_t* gA = (const uint8_t*)(A + (size_t)bz * CH * SP);
  const uint8_t* gB = (const uint8_t*)(B + (size_t)bz * HWP * SP);

  const int r2 = tid >> 3;            // 0..31: row within a 32-row staging call
  const int slot = tid & 7;
  const int csw = (slot - r2) & 7;    // global 16B chunk this lane fetches
  const int wb16 = (tid & ~63) * 16;  // wave-uniform LDS byte base (1KB/wave/call)

  const int wr = (wv >> 1) * 64;      // m offset within tile
  const int wc = (wv & 1) * 32;       // n offset within tile
  const int ml = lane & 15;
  const int kg = lane >> 4;           // 16B chunk within 64B k-slice

  f32x4 acc[4][2];
#pragma unroll
  for (int i = 0; i < 4; i++)
#pragma unroll
    for (int jj = 0; jj < 2; jj++) acc[i][jj] = (f32x4){0.f, 0.f, 0.f, 0.f};

  // stage one 32-row block (4 KB): A i=0..3 (128 rows), B i=0..1 (64 rows)
  auto stA = [&](int t, int bufi, int i) {
    load_lds16(gA + (size_t)(m0 + i * 32 + r2) * (SP * 2) + t * 128 + csw * 16,
               &lA[bufi][i * 4096 + wb16]);
  };
  auto stB = [&](int t, int bufi, int i) {
    load_lds16(gB + (size_t)(n0 + i * 32 + r2) * (SP * 2) + t * 128 + csw * 16,
               &lB[bufi][i * 4096 + wb16]);
  };

  // frag read: row r, k-slice s -> chunk c = s*4+kg at slot (c+r)&7
  auto rdf = [&](const uint8_t* base, int r, int s) -> short8 {
    return *reinterpret_cast<const short8*>(
        base + (r << 7) + (((s * 4 + kg) + r) & 7) * 16);
  };

  // prologue
  stA(0, 0, 0); stA(0, 0, 1); stA(0, 0, 2); stA(0, 0, 3);
  stB(0, 0, 0); stB(0, 0, 1);
  asm volatile("s_waitcnt vmcnt(0)" ::: "memory");
  __builtin_amdgcn_s_barrier();

  for (int t = 0; t < PVNT; t++) {
    const int cur = t & 1;
    const int nxt = cur ^ 1;
    const bool s1 = (t + 1 < PVNT);
    if (s1) {
      stA(t + 1, nxt, 0); stA(t + 1, nxt, 1); stA(t + 1, nxt, 2); stA(t + 1, nxt, 3);
      stB(t + 1, nxt, 0); stB(t + 1, nxt, 1);
    }
    const uint8_t* pA = lA[cur];
    const uint8_t* pB = lB[cur];
    short8 af[2][4], bq[2][2];
#pragma unroll
    for (int s = 0; s < 2; s++) {
#pragma unroll
      for (int mt = 0; mt < 4; mt++) af[s][mt] = rdf(pA, wr + mt * 16 + ml, s);
#pragma unroll
      for (int nt = 0; nt < 2; nt++) bq[s][nt] = rdf(pB, wc + nt * 16 + ml, s);
    }
    asm volatile("s_waitcnt lgkmcnt(0)");
#pragma unroll
    for (int s = 0; s < 2; s++)
#pragma unroll
      for (int mt = 0; mt < 4; mt++)
#pragma unroll
        for (int nt = 0; nt < 2; nt++)
          acc[mt][nt] = __builtin_amdgcn_mfma_f32_16x16x32_bf16(
              af[s][mt], bq[s][nt], acc[mt][nt], 0, 0, 0);
    if (s1) asm volatile("s_waitcnt vmcnt(0)" ::: "memory");
    __builtin_amdgcn_s_barrier();
  }

  const size_t obase = (size_t)bz * CH * HW;
  const size_t attoff = (size_t)BD * CH * HW;
  const int rq = (lane >> 4) * 4;
  const int cl = lane & 15;
#pragma unroll
  for (int mt = 0; mt < 4; mt++) {
    const int rb = m0 + wr + mt * 16 + rq;   // c
#pragma unroll
    for (int nt = 0; nt < 2; nt++) {
      const int col = n0 + wc + nt * 16 + cl;  // q
      if (col < HW) {
        f32x4 v = acc[mt][nt];
#pragma unroll
        for (int r = 0; r < 4; r++) {
          const int c = rb + r;
          size_t oi = obase + (size_t)c * HW + col;
          float att = v[r];
          out[oi] = (fqin[oi] + 0.3f * att) * (1.0f / 1.3f);
          out[attoff + oi] = att;
        }
      }
    }
  }
}

extern "C" void kernel_launch(void* const* d_in, const int* in_sizes, int n_in,
                              void* d_out, int out_size, void* d_ws, size_t ws_size,
                              hipStream_t stream) {
  const float* fqf = (const float*)d_in[0];   // [L,B,C,H,W]
  const float* fsf = (const float*)d_in[1];
  const float* f_q = (const float*)d_in[2];   // [B,CH,H,W]
  const float* f_s = (const float*)d_in[3];
  const float* cw  = (const float*)d_in[4];   // [L]
  float* out = (float*)d_out;

  // workspace: An, Bn (fp8), red (bf16), part (ssq partials);
  // attn + vb alias An/Bn after gemm
  char* w = (char*)d_ws;
  uint8_t* An = (uint8_t*)w;   w += (size_t)BD * HWP * KD;        // 45.6 MB
  uint8_t* Bn = (uint8_t*)w;   w += (size_t)BD * HWP * KD;        // 45.6 MB
  __hip_bfloat16* red = (__hip_bfloat16*)w;  w += (size_t)BD * HWP * SP * 2;  // 55.1 MB
  float* part = (float*)w;                                        // 1.5 MB
  __hip_bfloat16* attn = (__hip_bfloat16*)An;                     // 55.1 of 91.2 MB
  __hip_bfloat16* vb = (__hip_bfloat16*)(An + (size_t)BD * HWP * SP * 2);  // 3.8 MB
  (void)ws_size; (void)in_sizes; (void)n_in; (void)out_size;

  norm_k<<<dim3(15, NPLANE, 8), 256, 0, stream>>>(fqf, fsf, part);
  trans_k<<<dim3(57, NPLANE, 4), 256, 0, stream>>>(fqf, fsf, cw, part, An, Bn);
  gemm_main<<<dim3(450), 512, 0, stream>>>(An, Bn, red);
  softmax_k<<<dim3(HW, BD), 256, 0, stream>>>(red, attn);
  castv_k<<<(BD * CH * SP + 255) / 256, 256, 0, stream>>>(f_s, vb);
  pv_gemm<<<dim3(58, 2, BD), 256, 0, stream>>>(vb, attn, f_q, out);
}

// Round 4
// 766.663 us; speedup vs baseline: 1.1343x; 1.0443x over previous
//
#include <hip/hip_runtime.h>
#include <hip/hip_bf16.h>
#include <stdint.h>

// Problem constants
#define L3D 3
#define BD 2
#define CD 2048
#define HW 3600
#define CH 256
#define HWP 3712   // 29 * 128, padded hw
#define KD 6144    // L3D * CD  (bytes per row in fp8 An/Bn)
#define SP 3712    // padded support dim
#define SP2 3840   // partial-ssq q stride
#define LB6 6      // L3D*BD
#define NPLANE 12  // both inputs' (l,b) planes
#define NT 48      // K-tiles in main GEMM: KD / 128
#define PVNT 58    // K-steps in PV GEMM: SP / 64

typedef __attribute__((ext_vector_type(8))) short short8;
typedef __attribute__((ext_vector_type(4))) float f32x4;
typedef __attribute__((ext_vector_type(4))) int i32x4;
typedef __attribute__((ext_vector_type(8))) int i32x8;

__device__ __forceinline__ short f2bf(float v) {
  uint32_t x = __float_as_uint(v);
  uint32_t r = (x + 0x7FFFu + ((x >> 16) & 1u)) >> 16;   // RNE
  return (short)(r & 0xFFFFu);
}

__device__ __forceinline__ float bf2f(short s) {
  return __uint_as_float(((uint32_t)(uint16_t)s) << 16);
}

__device__ __forceinline__ void load_lds16(const void* g, void* l) {
  __builtin_amdgcn_global_load_lds(
      (const __attribute__((address_space(1))) void*)g,
      (__attribute__((address_space(3))) void*)l, 16, 0, 0);
}

// ---------------- norm_k: sum-of-squares partials ----------------
__global__ __launch_bounds__(256) void norm_k(const float* __restrict__ fq,
                                              const float* __restrict__ fs,
                                              float* __restrict__ part) {
  const int qt = blockIdx.x * 256;
  const int j = blockIdx.y;
  const int cs = blockIdx.z;
  const bool isq = (j < LB6);
  const int lb = isq ? j : j - LB6;
  const float* x = (isq ? fq : fs) + (size_t)lb * CD * HW;

  const int tid = threadIdx.x;
  const int qg = tid & 63;
  const int cp = tid >> 6;          // 0..3
  const int q4 = qt + qg * 4;

  f32x4 a0 = (f32x4){0.f, 0.f, 0.f, 0.f};
  f32x4 a1 = a0, a2 = a0, a3 = a0;
  if (q4 < HW) {                    // HW % 4 == 0: float4 fully valid or fully out
    const float* p = x + ((size_t)cs * 256 + cp) * HW + q4;
    for (int i = 0; i < 64; i += 4) {
      f32x4 v0 = *reinterpret_cast<const f32x4*>(p + (size_t)(i + 0) * 4 * HW);
      f32x4 v1 = *reinterpret_cast<const f32x4*>(p + (size_t)(i + 1) * 4 * HW);
      f32x4 v2 = *reinterpret_cast<const f32x4*>(p + (size_t)(i + 2) * 4 * HW);
      f32x4 v3 = *reinterpret_cast<const f32x4*>(p + (size_t)(i + 3) * 4 * HW);
      a0 += v0 * v0; a1 += v1 * v1; a2 += v2 * v2; a3 += v3 * v3;
    }
  }
  f32x4 a = (a0 + a1) + (a2 + a3);

  __shared__ float rb[4][256];
  *reinterpret_cast<f32x4*>(&rb[cp][qg * 4]) = a;
  __syncthreads();
  float s = rb[0][tid] + rb[1][tid] + rb[2][tid] + rb[3][tid];
  part[((size_t)cs * NPLANE + j) * SP2 + qt + tid] = s;
}

// ---------------- trans_k: normalize + transpose + fp8 pack ----------------
__global__ __launch_bounds__(256) void trans_k(const float* __restrict__ fq,
                                               const float* __restrict__ fs,
                                               const float* __restrict__ cw,
                                               const float* __restrict__ part,
                                               uint8_t* __restrict__ An,
                                               uint8_t* __restrict__ Bn) {
  const int j = blockIdx.y;
  const int qt = blockIdx.x * 64;
  const int cg = blockIdx.z;
  const bool isq = (j < LB6);
  const int lb = isq ? j : j - LB6;
  const int l = lb / BD, b = lb % BD;
  const float* x = (isq ? fq : fs) + (size_t)lb * CD * HW;
  uint8_t* dst = isq ? An : Bn;

  const int tid = threadIdx.x;

  __shared__ float ivs[64];
  if (tid < 64) {
    const int q = qt + tid;
    float s = 0.f;
#pragma unroll
    for (int cs = 0; cs < 8; cs++) s += part[((size_t)cs * NPLANE + j) * SP2 + q];
    const float scale = isq ? (cw[l] * 32.0f) : 32.0f;  // fp8 range scaling
    ivs[tid] = (1.f / fmaxf(sqrtf(s), 1e-12f)) * scale;
  }

  __shared__ float tile[64][65];
  const int tx = tid & 63, partid = tid >> 6;
  const int q = qt + tx;
  const int wx = tid & 7, wy = tid >> 3;

  for (int t = 0; t < 8; t++) {
    const int ct = cg * 8 + t;
    const float* px = x + (size_t)ct * 64 * HW;
    __syncthreads();
#pragma unroll
    for (int r = 0; r < 16; r++) {
      int cl = r * 4 + partid;
      tile[cl][tx] = (q < HW) ? px[(size_t)cl * HW + q] : 0.f;
    }
    __syncthreads();
#pragma unroll
    for (int it = 0; it < 2; it++) {
      int qrow = wy + it * 32;
      int qq = qt + qrow;
      if (qq < HW) {
        float iv = ivs[qrow];
        float v[8];
#pragma unroll
        for (int jj = 0; jj < 8; jj++) v[jj] = tile[wx * 8 + jj][qrow] * iv;
        int lo = 0, hi = 0;
        lo = __builtin_amdgcn_cvt_pk_fp8_f32(v[0], v[1], lo, false);
        lo = __builtin_amdgcn_cvt_pk_fp8_f32(v[2], v[3], lo, true);
        hi = __builtin_amdgcn_cvt_pk_fp8_f32(v[4], v[5], hi, false);
        hi = __builtin_amdgcn_cvt_pk_fp8_f32(v[6], v[7], hi, true);
        int2 pk = make_int2(lo, hi);
        *reinterpret_cast<int2*>(dst + ((size_t)b * HWP + qq) * KD +
                                 (size_t)l * CD + ct * 64 + wx * 8) = pk;
      }
    }
  }
}

// ---------------- Main GEMM: MX-fp8, 256x256 tile, BK=128, FAT 2-phase ----------------
// ONE barrier + ONE vmcnt(0) per K-tile (vs 8 barriers before). Per tile:
//   read A-low + B frags (16 ds_read_b128) from cur; issue ALL 8 staging loads
//   (t+1 -> nxt); MFMA cluster 1 (m-low x n-all); read A-high (8); MFMA cluster 2;
//   vmcnt(0) [loads issued ~2500cy earlier -> near-zero wait]; s_barrier.
// No mid-phase barriers: compiler emits fine-grained lgkmcnt so each wave starts
// MFMA as soon as its OWN reads land; waves drift within the tile so LDS reads of
// one wave overlap MFMAs of another (pipe overlap instead of alternation).
// Hazards: tile-t reads only from cur; staging writes only to nxt; reads are
// dataflow-complete before the tile-end barrier.
// LDS layout: row = 128 B = 8 chunks of 16 B; chunk c of row r at slot (c+r)&7.
// Bijective XCD swizzle (450 blocks): m-major A-panel-sharing groups per XCD L2.
__global__ __launch_bounds__(512, 2) void gemm_main(const uint8_t* __restrict__ A,
                                                    const uint8_t* __restrict__ B,
                                                    __hip_bfloat16* __restrict__ C) {
  // --- bijective XCD swizzle: 450 = 8*56 + 2 -> chunks {57,57,56,56,56,56,56,56}
  const int orig = blockIdx.x;
  const int xcd = orig & 7, idx = orig >> 3;
  const int wg = (xcd < 2 ? xcd * 57 : 114 + (xcd - 2) * 56) + idx;
  const int bz = wg / 225;
  const int lin = wg % 225;
  const int m_t = lin / 15, n_t = lin % 15;   // m-major: 15 consecutive share A-panel
  const int m0 = m_t * 256, n0 = n_t * 256;
  const int tid = threadIdx.x;
  const int lane = tid & 63;
  const int wv = tid >> 6;               // 0..7 waves: 2 (m) x 4 (n)

  __shared__ uint8_t lA[2][256 * 128];   // 64 KB
  __shared__ uint8_t lB[2][256 * 128];   // 64 KB

  const uint8_t* gA = A + (size_t)bz * HWP * KD;
  const uint8_t* gB = B + (size_t)bz * HWP * KD;

  const int r_loc = tid >> 3;            // 0..63: row within a 64-row staging call
  const int slot = tid & 7;              // LDS slot within row
  const int csw = (slot - r_loc) & 7;    // global chunk this lane fetches
  const int wavebase = (tid & ~63) * 16; // wave-uniform LDS byte base

  const int wr = (wv >> 2) * 128;        // wave m offset: 0 / 128
  const int wc = (wv & 3) * 64;          // wave n offset: 0/64/128/192
  const int ml = lane & 15;
  const int kg = lane >> 4;              // k-group: 32 contiguous k bytes per lane

  f32x4 acc[8][4];
#pragma unroll
  for (int i = 0; i < 8; i++)
#pragma unroll
    for (int jj = 0; jj < 4; jj++) acc[i][jj] = (f32x4){0.f, 0.f, 0.f, 0.f};

  auto stA = [&](int t, int bufi, int i) {
    load_lds16(gA + (size_t)(m0 + i * 64 + r_loc) * KD + t * 128 + csw * 16,
               &lA[bufi][i * 8192 + wavebase]);
  };
  auto stB = [&](int t, int bufi, int i) {
    load_lds16(gB + (size_t)(n0 + i * 64 + r_loc) * KD + t * 128 + csw * 16,
               &lB[bufi][i * 8192 + wavebase]);
  };

  auto rdfrag = [&](const uint8_t* base, int row) -> i32x8 {
    const uint8_t* rp = base + (row << 7);
    i32x4 lo = *reinterpret_cast<const i32x4*>(rp + (((kg * 2)     + row) & 7) * 16);
    i32x4 hi = *reinterpret_cast<const i32x4*>(rp + (((kg * 2 + 1) + row) & 7) * 16);
    return __builtin_shufflevector(lo, hi, 0, 1, 2, 3, 4, 5, 6, 7);
  };

  // prologue: stage tile 0, drain, barrier
  stA(0, 0, 0); stA(0, 0, 1); stA(0, 0, 2); stA(0, 0, 3);
  stB(0, 0, 0); stB(0, 0, 1); stB(0, 0, 2); stB(0, 0, 3);
  asm volatile("s_waitcnt vmcnt(0)" ::: "memory");
  __builtin_amdgcn_s_barrier();

  for (int t = 0; t < NT; t++) {
    const int cur = t & 1;
    const int nxt = cur ^ 1;
    const uint8_t* pA = lA[cur];
    const uint8_t* pB = lB[cur];
    const bool s1 = (t + 1 < NT);
    i32x8 afl[4], afh[4], bfr[4];

    // reads for cluster 1: A m-low + B all
#pragma unroll
    for (int x = 0; x < 4; x++) afl[x] = rdfrag(pA, wr + x * 16 + ml);
#pragma unroll
    for (int x = 0; x < 4; x++) bfr[x] = rdfrag(pB, wc + x * 16 + ml);

    // stage tile t+1 fully (8 loads) -> in flight across both MFMA clusters
    if (s1) {
      stA(t + 1, nxt, 0); stA(t + 1, nxt, 1); stA(t + 1, nxt, 2); stA(t + 1, nxt, 3);
      stB(t + 1, nxt, 0); stB(t + 1, nxt, 1); stB(t + 1, nxt, 2); stB(t + 1, nxt, 3);
    }

    // MFMA cluster 1: m-low x n-all (compiler inserts partial lgkmcnt)
    __builtin_amdgcn_s_setprio(1);
#pragma unroll
    for (int mt = 0; mt < 4; mt++)
#pragma unroll
      for (int nt = 0; nt < 4; nt++)
        acc[mt][nt] = __builtin_amdgcn_mfma_scale_f32_16x16x128_f8f6f4(
            afl[mt], bfr[nt], acc[mt][nt], 0, 0, 0, 0x7F7F7F7F, 0, 0x7F7F7F7F);
    __builtin_amdgcn_s_setprio(0);

    // reads for cluster 2: A m-high
#pragma unroll
    for (int x = 0; x < 4; x++) afh[x] = rdfrag(pA, wr + 64 + x * 16 + ml);

    // MFMA cluster 2: m-high x n-all
    __builtin_amdgcn_s_setprio(1);
#pragma unroll
    for (int mt = 0; mt < 4; mt++)
#pragma unroll
      for (int nt = 0; nt < 4; nt++)
        acc[4 + mt][nt] = __builtin_amdgcn_mfma_scale_f32_16x16x128_f8f6f4(
            afh[mt], bfr[nt], acc[4 + mt][nt], 0, 0, 0, 0x7F7F7F7F, 0, 0x7F7F7F7F);
    __builtin_amdgcn_s_setprio(0);

    // staged loads were issued ~2500 cycles ago -> near-zero wait here
    if (s1) asm volatile("s_waitcnt vmcnt(0)" ::: "memory");
    __builtin_amdgcn_s_barrier();
  }

  __hip_bfloat16* oc = C + (size_t)bz * HWP * SP;
  const int rq = (lane >> 4) * 4;
  const int cl = lane & 15;
#pragma unroll
  for (int mt = 0; mt < 8; mt++) {
    const int rb = m0 + wr + mt * 16 + rq;
#pragma unroll
    for (int nt = 0; nt < 4; nt++) {
      const int col = n0 + wc + nt * 16 + cl;
      if (col < SP) {
        f32x4 v = acc[mt][nt];
#pragma unroll
        for (int r = 0; r < 4; r++) {
          const int rr = rb + r;
          if (rr < HW) *reinterpret_cast<short*>(&oc[(size_t)rr * SP + col]) = f2bf(v[r]);
        }
      }
    }
  }
}

// ---------------- Row softmax: bf16 red -> bf16 attn (pad cols zeroed) ----------------
__global__ __launch_bounds__(256) void softmax_k(const __hip_bfloat16* __restrict__ red,
                                                 __hip_bfloat16* __restrict__ attn) {
  const int q = blockIdx.x;
  const int b = blockIdx.y;
  const __hip_bfloat16* row = red + ((size_t)b * HWP + q) * SP;
  __hip_bfloat16* orow = attn + ((size_t)b * HWP + q) * SP;
  const int tid = threadIdx.x;
  const int lane = tid & 63, wv = tid >> 6;
  const float SM = 20.0f / 1024.0f;   // undo 32*32 fp8 range scaling, apply temp

  float v0[8], v1[8];
  const int c1 = 256 + tid;           // second chunk id (valid when < 450)
  const bool has1 = (c1 < 450);

  float mx = -3.4e38f;
  {
    short8 pk = *reinterpret_cast<const short8*>(&row[(size_t)tid * 8]);
#pragma unroll
    for (int j = 0; j < 8; j++) { v0[j] = bf2f(pk[j]); mx = fmaxf(mx, v0[j]); }
  }
  if (has1) {
    short8 pk = *reinterpret_cast<const short8*>(&row[(size_t)c1 * 8]);
#pragma unroll
    for (int j = 0; j < 8; j++) { v1[j] = bf2f(pk[j]); mx = fmaxf(mx, v1[j]); }
  }
  for (int off = 32; off > 0; off >>= 1) mx = fmaxf(mx, __shfl_down(mx, off, 64));
  __shared__ float sm[4];
  if (lane == 0) sm[wv] = mx;
  __syncthreads();
  mx = fmaxf(fmaxf(sm[0], sm[1]), fmaxf(sm[2], sm[3]));

  float sum = 0.f;
#pragma unroll
  for (int j = 0; j < 8; j++) { float e = __expf((v0[j] - mx) * SM); v0[j] = e; sum += e; }
  if (has1) {
#pragma unroll
    for (int j = 0; j < 8; j++) { float e = __expf((v1[j] - mx) * SM); v1[j] = e; sum += e; }
  }
  for (int off = 32; off > 0; off >>= 1) sum += __shfl_down(sum, off, 64);
  __syncthreads();
  if (lane == 0) sm[wv] = sum;
  __syncthreads();
  const float inv = 1.f / (sm[0] + sm[1] + sm[2] + sm[3]);

  {
    short8 o;
#pragma unroll
    for (int j = 0; j < 8; j++) o[j] = f2bf(v0[j] * inv);
    *reinterpret_cast<short8*>(&orow[(size_t)tid * 8]) = o;
  }
  if (has1) {
    short8 o;
#pragma unroll
    for (int j = 0; j < 8; j++) o[j] = f2bf(v1[j] * inv);
    *reinterpret_cast<short8*>(&orow[(size_t)c1 * 8]) = o;
  } else if (c1 < 464) {            // pad chunks 450..463 -> zero (pv reads them)
    short8 z = {0, 0, 0, 0, 0, 0, 0, 0};
    *reinterpret_cast<short8*>(&orow[(size_t)c1 * 8]) = z;
  }
}

// ---------------- Cast f_s -> bf16 v, zero-pad s to SP ----------------
__global__ __launch_bounds__(256) void castv_k(const float* __restrict__ fs,
                                               __hip_bfloat16* __restrict__ vb) {
  const int idx = blockIdx.x * 256 + threadIdx.x;
  if (idx >= BD * CH * SP) return;
  const int s = idx % SP;
  const int bc = idx / SP;
  float v = (s < HW) ? fs[(size_t)bc * HW + s] : 0.f;
  *reinterpret_cast<short*>(&vb[idx]) = f2bf(v);
}

// ---------------- PV GEMM + blend epilogue, 128(c) x 64(q), BK=64, 2-phase dbuf ----
__global__ __launch_bounds__(256, 2) void pv_gemm(const __hip_bfloat16* __restrict__ A,
                                                  const __hip_bfloat16* __restrict__ B,
                                                  const float* __restrict__ fqin,
                                                  float* __restrict__ out) {
  const int bz = blockIdx.z;
  const int m0 = blockIdx.y * 128;   // c tile (2)
  const int n0 = blockIdx.x * 64;    // q tile (58)
  const int tid = threadIdx.x;
  const int lane = tid & 63;
  const int wv = tid >> 6;

  __shared__ uint8_t lA[2][128 * 128];   // 16 KB each: 128 c-rows x 128 B (BK=64 bf16)
  __shared__ uint8_t lB[2][64 * 128];    // 8 KB each   -> 48 KB total

  const uint8_t* gA = (const uint8_t*)(A + (size_t)bz * CH * SP);
  const uint8_t* gB = (const uint8_t*)(B + (size_t)bz * HWP * SP);

  const int r2 = tid >> 3;            // 0..31: row within a 32-row staging call
  const int slot = tid & 7;
  const int csw = (slot - r2) & 7;    // global 16B chunk this lane fetches
  const int wb16 = (tid & ~63) * 16;  // wave-uniform LDS byte base (1KB/wave/call)

  const int wr = (wv >> 1) * 64;      // m offset within tile
  const int wc = (wv & 1) * 32;       // n offset within tile
  const int ml = lane & 15;
  const int kg = lane >> 4;           // 16B chunk within 64B k-slice

  f32x4 acc[4][2];
#pragma unroll
  for (int i = 0; i < 4; i++)
#pragma unroll
    for (int jj = 0; jj < 2; jj++) acc[i][jj] = (f32x4){0.f, 0.f, 0.f, 0.f};

  auto stA = [&](int t, int bufi, int i) {
    load_lds16(gA + (size_t)(m0 + i * 32 + r2) * (SP * 2) + t * 128 + csw * 16,
               &lA[bufi][i * 4096 + wb16]);
  };
  auto stB = [&](int t, int bufi, int i) {
    load_lds16(gB + (size_t)(n0 + i * 32 + r2) * (SP * 2) + t * 128 + csw * 16,
               &lB[bufi][i * 4096 + wb16]);
  };

  auto rdf = [&](const uint8_t* base, int r, int s) -> short8 {
    return *reinterpret_cast<const short8*>(
        base + (r << 7) + (((s * 4 + kg) + r) & 7) * 16);
  };

  // prologue
  stA(0, 0, 0); stA(0, 0, 1); stA(0, 0, 2); stA(0, 0, 3);
  stB(0, 0, 0); stB(0, 0, 1);
  asm volatile("s_waitcnt vmcnt(0)" ::: "memory");
  __builtin_amdgcn_s_barrier();

  for (int t = 0; t < PVNT; t++) {
    const int cur = t & 1;
    const int nxt = cur ^ 1;
    const bool s1 = (t + 1 < PVNT);
    if (s1) {
      stA(t + 1, nxt, 0); stA(t + 1, nxt, 1); stA(t + 1, nxt, 2); stA(t + 1, nxt, 3);
      stB(t + 1, nxt, 0); stB(t + 1, nxt, 1);
    }
    const uint8_t* pA = lA[cur];
    const uint8_t* pB = lB[cur];
    short8 af[2][4], bq[2][2];
#pragma unroll
    for (int s = 0; s < 2; s++) {
#pragma unroll
      for (int mt = 0; mt < 4; mt++) af[s][mt] = rdf(pA, wr + mt * 16 + ml, s);
#pragma unroll
      for (int nt = 0; nt < 2; nt++) bq[s][nt] = rdf(pB, wc + nt * 16 + ml, s);
    }
    asm volatile("s_waitcnt lgkmcnt(0)");
#pragma unroll
    for (int s = 0; s < 2; s++)
#pragma unroll
      for (int mt = 0; mt < 4; mt++)
#pragma unroll
        for (int nt = 0; nt < 2; nt++)
          acc[mt][nt] = __builtin_amdgcn_mfma_f32_16x16x32_bf16(
              af[s][mt], bq[s][nt], acc[mt][nt], 0, 0, 0);
    if (s1) asm volatile("s_waitcnt vmcnt(0)" ::: "memory");
    __builtin_amdgcn_s_barrier();
  }

  const size_t obase = (size_t)bz * CH * HW;
  const size_t attoff = (size_t)BD * CH * HW;
  const int rq = (lane >> 4) * 4;
  const int cl = lane & 15;
#pragma unroll
  for (int mt = 0; mt < 4; mt++) {
    const int rb = m0 + wr + mt * 16 + rq;   // c
#pragma unroll
    for (int nt = 0; nt < 2; nt++) {
      const int col = n0 + wc + nt * 16 + cl;  // q
      if (col < HW) {
        f32x4 v = acc[mt][nt];
#pragma unroll
        for (int r = 0; r < 4; r++) {
          const int c = rb + r;
          size_t oi = obase + (size_t)c * HW + col;
          float att = v[r];
          out[oi] = (fqin[oi] + 0.3f * att) * (1.0f / 1.3f);
          out[attoff + oi] = att;
        }
      }
    }
  }
}

extern "C" void kernel_launch(void* const* d_in, const int* in_sizes, int n_in,
                              void* d_out, int out_size, void* d_ws, size_t ws_size,
                              hipStream_t stream) {
  const float* fqf = (const float*)d_in[0];   // [L,B,C,H,W]
  const float* fsf = (const float*)d_in[1];
  const float* f_q = (const float*)d_in[2];   // [B,CH,H,W]
  const float* f_s = (const float*)d_in[3];
  const float* cw  = (const float*)d_in[4];   // [L]
  float* out = (float*)d_out;

  char* w = (char*)d_ws;
  uint8_t* An = (uint8_t*)w;   w += (size_t)BD * HWP * KD;        // 45.6 MB
  uint8_t* Bn = (uint8_t*)w;   w += (size_t)BD * HWP * KD;        // 45.6 MB
  __hip_bfloat16* red = (__hip_bfloat16*)w;  w += (size_t)BD * HWP * SP * 2;  // 55.1 MB
  float* part = (float*)w;                                        // 1.5 MB
  __hip_bfloat16* attn = (__hip_bfloat16*)An;                     // 55.1 of 91.2 MB
  __hip_bfloat16* vb = (__hip_bfloat16*)(An + (size_t)BD * HWP * SP * 2);  // 3.8 MB
  (void)ws_size; (void)in_sizes; (void)n_in; (void)out_size;

  norm_k<<<dim3(15, NPLANE, 8), 256, 0, stream>>>(fqf, fsf, part);
  trans_k<<<dim3(57, NPLANE, 4), 256, 0, stream>>>(fqf, fsf, cw, part, An, Bn);
  gemm_main<<<dim3(450), 512, 0, stream>>>(An, Bn, red);
  softmax_k<<<dim3(HW, BD), 256, 0, stream>>>(red, attn);
  castv_k<<<(BD * CH * SP + 255) / 256, 256, 0, stream>>>(f_s, vb);
  pv_gemm<<<dim3(58, 2, BD), 256, 0, stream>>>(vb, attn, f_q, out);
}